// Round 3
// baseline (399.157 us; speedup 1.0000x reference)
//
#include <hip/hip_runtime.h>
#include <hip/hip_bf16.h>

typedef __attribute__((ext_vector_type(8))) short bfrag8;   // 8 bf16 (4 VGPRs)
typedef __attribute__((ext_vector_type(4))) float f32x4;    // MFMA C/D frag

__device__ __forceinline__ unsigned short f2bf(float f) {
  unsigned int u = __float_as_uint(f);
  u += 0x7FFFu + ((u >> 16) & 1u);   // RNE
  return (unsigned short)(u >> 16);
}

// torchvision _interp_axis semantics (aligned=false)
__device__ __forceinline__ void interp1(float t, int size, int& lo, int& hi, float& frac, bool& valid) {
  valid = (t > -1.0f) && (t < (float)size);
  t = fmaxf(t, 0.0f);
  lo = (int)t;                      // t>=0 so trunc == floor
  if (lo > size - 1) lo = size - 1;
  hi = lo + 1; if (hi > size - 1) hi = size - 1;
  if (lo >= size - 1) t = (float)lo;
  frac = t - (float)lo;
}

// ---------- K1: RoI align -> A[256][37632] bf16, k = c*49 + (ph*7+pw)  (W1-natural order) ----------
// grid 1024: block = (box n, channel-quarter q). 192 threads, thread owns channel c = q*192+t.
// Compute into LDS [192][49], then fully-coalesced u32 copy-out (c-major region is contiguous).
__global__ __launch_bounds__(192) void roi_kernel(const float* __restrict__ fmap,
                                                  const float* __restrict__ boxes,
                                                  unsigned short* __restrict__ A) {
  const int bid = blockIdx.x;
  const int n = bid >> 2, q = bid & 3;
  const int t = threadIdx.x;
  __shared__ unsigned short T[192 * 49];   // [tc][bin], 18816 B

  const float* bx = boxes + n * 5;
  const int b = (int)bx[0];
  const float x1 = bx[1], y1 = bx[2], x2 = bx[3], y2 = bx[4];
  const float bw = fmaxf(x2 - x1, 1.0f) * (1.0f / 7.0f);
  const float bh = fmaxf(y2 - y1, 1.0f) * (1.0f / 7.0f);

  const int c = q * 192 + t;
  const float* fb = fmap + (size_t)b * 64 * 64 * 768 + c;

  for (int ph = 0; ph < 7; ph++) {
    int yl[2], yh[2]; float ly[2], hy[2]; bool vy[2];
    #pragma unroll
    for (int sy = 0; sy < 2; sy++) {
      float y = y1 + (ph * 2 + sy + 0.5f) * 0.5f * bh;
      interp1(y, 64, yl[sy], yh[sy], ly[sy], vy[sy]);
      hy[sy] = 1.0f - ly[sy];
    }
    float acc[7];
    #pragma unroll
    for (int pw = 0; pw < 7; pw++) acc[pw] = 0.0f;

    #pragma unroll
    for (int pw = 0; pw < 7; pw++) {
      #pragma unroll
      for (int sx = 0; sx < 2; sx++) {
        float x = x1 + (pw * 2 + sx + 0.5f) * 0.5f * bw;
        int xl, xh; float lx; bool vx;
        interp1(x, 64, xl, xh, lx, vx);
        float hx = 1.0f - lx;
        if (vx) {
          #pragma unroll
          for (int sy = 0; sy < 2; sy++) {
            if (vy[sy]) {   // box-uniform: wave-coherent branch
              float v00 = fb[(yl[sy] * 64 + xl) * 768];
              float v01 = fb[(yl[sy] * 64 + xh) * 768];
              float v10 = fb[(yh[sy] * 64 + xl) * 768];
              float v11 = fb[(yh[sy] * 64 + xh) * 768];
              acc[pw] += hy[sy] * (hx * v00 + lx * v01) + ly[sy] * (hx * v10 + lx * v11);
            }
          }
        }
      }
      T[t * 49 + ph * 7 + pw] = f2bf(acc[pw] * 0.25f);
    }
  }
  __syncthreads();
  // coalesced copy-out: block's region = A[n][q*192*49 .. +9408] shorts = 18816 B (4-aligned)
  const unsigned* Ts = (const unsigned*)T;
  unsigned* out = (unsigned*)(A + (size_t)n * 37632 + q * 9408);
  #pragma unroll 4
  for (int i = t; i < 4704; i += 192) out[i] = Ts[i];
}

// ---------- K2/K4: split-K bf16 MFMA GEMM, BM=256 BN=64 BK=64 ----------
// A [256][KT] bf16 row-major (global_load_lds, source-swizzled, linear LDS dest).
// B [KT][NT] fp32 row-major, k-tile rows CONSECUTIVE (no permutation) -> coalesced 256-B segments.
// grid 1D = NKS*NNT, XCD-swizzled so all NNT n-tiles of a ks-chunk share an XCD (A L2 reuse).
template<int KT, int NT, int STEPS, int NNT>
__global__ __launch_bounds__(256, 2) void gemm_splitk(const unsigned short* __restrict__ A,
                                                      const float* __restrict__ B,
                                                      float* __restrict__ part) {
  __shared__ unsigned short Al[2][256 * 64];   // 64 KB, rows 128 B, content swizzled key (r&7)
  __shared__ unsigned short Bl[2][64 * 64];    // 16 KB, [n][k] rows 128 B, swizzled key (n>>3)&7

  const int nwg = gridDim.x;
  const int bid = blockIdx.x;
  const int work = (bid & 7) * (nwg >> 3) + (bid >> 3);
  const int ks = work / NNT;
  const int nt = work - ks * NNT;
  const int n0 = nt * 64;
  const int k0 = ks * (STEPS * 64);

  const int t = (int)threadIdx.x;
  const int lane = t & 63, wid = t >> 6;

  f32x4 acc[4][4];
  #pragma unroll
  for (int i = 0; i < 4; i++)
    #pragma unroll
    for (int j = 0; j < 4; j++) acc[i][j] = (f32x4){0.f, 0.f, 0.f, 0.f};

  // B staging registers — NAMED, never address-taken (rule #20)
  float4 b00, b01, b10, b11;

  auto issueA = [&](int buf, int s) {
    #pragma unroll
    for (int i = 0; i < 8; i++) {
      const int r0 = wid * 64 + i * 8;               // 8 rows per 1KB instr
      const int row = r0 + (lane >> 3);
      const int j = (lane & 7) ^ (row & 7);          // pre-swizzled global slot
      const unsigned short* g = A + (size_t)row * KT + (k0 + s * 64 + j * 8);
      __builtin_amdgcn_global_load_lds(
          (const __attribute__((address_space(1))) void*)g,
          (__attribute__((address_space(3))) void*)&Al[buf][r0 * 64],
          16, 0, 0);
    }
  };

  // rows r = (t>>4)*2 + {0,1} + 32g  (consecutive rows; 16 lanes cover one row's 256 B)
  auto loadB = [&](int s) {
    const float* p = B + (size_t)(k0 + s * 64 + (t >> 4) * 2) * NT + n0 + (t & 15) * 4;
    b00 = *(const float4*)p;
    b01 = *(const float4*)(p + NT);
    b10 = *(const float4*)(p + 32 * (size_t)NT);
    b11 = *(const float4*)(p + 33 * (size_t)NT);
  };

  auto writeB = [&](int buf) {
    char* base = (char*)&Bl[buf][0];
    const int lo = ((t >> 4) & 3) * 4;      // byte-in-slot (k-pair position)
    const int nb = (t & 15) * 4;
    #define WRB(g, j, fa, fb_) { \
      int nn = nb + j; \
      int slot = (g) * 4 + wid; \
      unsigned v = (unsigned)f2bf(fa) | ((unsigned)f2bf(fb_) << 16); \
      *(unsigned*)(base + nn * 128 + ((slot ^ ((nn >> 3) & 7)) << 4) + lo) = v; }
    WRB(0, 0, b00.x, b01.x) WRB(0, 1, b00.y, b01.y)
    WRB(0, 2, b00.z, b01.z) WRB(0, 3, b00.w, b01.w)
    WRB(1, 0, b10.x, b11.x) WRB(1, 1, b10.y, b11.y)
    WRB(1, 2, b10.z, b11.z) WRB(1, 3, b10.w, b11.w)
    #undef WRB
  };

  auto compute = [&](int buf) {
    const char* abase = (const char*)&Al[buf][0];
    const char* bbase = (const char*)&Bl[buf][0];
    #pragma unroll
    for (int kk = 0; kk < 2; kk++) {
      const int slot = kk * 4 + (lane >> 4);
      bfrag8 af[4], bf[4];
      #pragma unroll
      for (int fm = 0; fm < 4; fm++) {
        const int r = wid * 64 + fm * 16 + (lane & 15);
        af[fm] = *(const bfrag8*)(abase + r * 128 + ((slot ^ (r & 7)) << 4));
      }
      #pragma unroll
      for (int fn = 0; fn < 4; fn++) {
        const int r = fn * 16 + (lane & 15);
        bf[fn] = *(const bfrag8*)(bbase + r * 128 + ((slot ^ ((r >> 3) & 7)) << 4));
      }
      #pragma unroll
      for (int fm = 0; fm < 4; fm++)
        #pragma unroll
        for (int fn = 0; fn < 4; fn++)
          acc[fm][fn] = __builtin_amdgcn_mfma_f32_16x16x32_bf16(af[fm], bf[fn], acc[fm][fn], 0, 0, 0);
    }
  };

  // prologue
  issueA(0, 0);
  loadB(0);
  writeB(0);
  __syncthreads();           // drains vmcnt(0): A-DMA + B loads complete

  int buf = 0;
  for (int s = 0; s < STEPS; s++) {
    if (s + 1 < STEPS) {
      issueA(buf ^ 1, s + 1);   // async DMA into other half
      loadB(s + 1);             // HBM latency hides under compute
    }
    compute(buf);
    if (s + 1 < STEPS) writeB(buf ^ 1);
    __syncthreads();
    buf ^= 1;
  }

  // epilogue: C/D layout col=lane&15, row=(lane>>4)*4+q
  const int r4 = (lane >> 4) * 4, cn = lane & 15;
  #pragma unroll
  for (int fm = 0; fm < 4; fm++)
    #pragma unroll
    for (int fn = 0; fn < 4; fn++)
      #pragma unroll
      for (int q = 0; q < 4; q++) {
        int m = wid * 64 + fm * 16 + r4 + q;
        part[((size_t)ks * 256 + m) * NT + n0 + fn * 16 + cn] = acc[fm][fn][q];
      }
}

// ---------- K3: reduce 28 partials + bias + relu -> h bf16 [256][1024] ----------
__global__ __launch_bounds__(256) void reduce_relu_28(const float* __restrict__ part,
                                                      const float* __restrict__ b1,
                                                      unsigned short* __restrict__ h) {
  const int i4 = blockIdx.x * 256 + threadIdx.x;   // over 65536 float4
  const float4* p4 = (const float4*)part;
  float4 s = p4[i4];
  #pragma unroll
  for (int p = 1; p < 28; p++) {
    float4 v = p4[(size_t)p * 65536 + i4];
    s.x += v.x; s.y += v.y; s.z += v.z; s.w += v.w;
  }
  float4 bb = ((const float4*)b1)[i4 & 255];
  s.x = fmaxf(s.x + bb.x, 0.f); s.y = fmaxf(s.y + bb.y, 0.f);
  s.z = fmaxf(s.z + bb.z, 0.f); s.w = fmaxf(s.w + bb.w, 0.f);
  uint2 pk;
  pk.x = (unsigned)f2bf(s.x) | ((unsigned)f2bf(s.y) << 16);
  pk.y = (unsigned)f2bf(s.z) | ((unsigned)f2bf(s.w) << 16);
  ((uint2*)h)[i4] = pk;
}

// ---------- K5: reduce 8 partials + bias -> out fp32 [256][512] ----------
__global__ __launch_bounds__(256) void reduce_bias_8(const float* __restrict__ part,
                                                     const float* __restrict__ b2,
                                                     float* __restrict__ out) {
  const int i4 = blockIdx.x * 256 + threadIdx.x;   // over 32768 float4
  const float4* p4 = (const float4*)part;
  float4 s = p4[i4];
  #pragma unroll
  for (int p = 1; p < 8; p++) {
    float4 v = p4[(size_t)p * 32768 + i4];
    s.x += v.x; s.y += v.y; s.z += v.z; s.w += v.w;
  }
  float4 bb = ((const float4*)b2)[i4 & 127];
  s.x += bb.x; s.y += bb.y; s.z += bb.z; s.w += bb.w;
  ((float4*)out)[i4] = s;
}

// ---------- launch ----------
extern "C" void kernel_launch(void* const* d_in, const int* in_sizes, int n_in,
                              void* d_out, int out_size, void* d_ws, size_t ws_size,
                              hipStream_t stream) {
  const float* fmap  = (const float*)d_in[0];
  const float* boxes = (const float*)d_in[1];
  const float* W1    = (const float*)d_in[2];
  const float* b1    = (const float*)d_in[3];
  const float* W2    = (const float*)d_in[4];
  const float* b2    = (const float*)d_in[5];
  float* out = (float*)d_out;

  char* ws = (char*)d_ws;
  unsigned short* Aroi = (unsigned short*)ws;                       // 19,267,584 B
  float* part1 = (float*)(ws + 19267584);                           // 29,360,128 B
  unsigned short* h = (unsigned short*)(ws + 19267584 + 29360128);  // 524,288 B
  float* part2 = (float*)(ws + 19267584 + 29360128 + 524288);       // 4,194,304 B

  // K1: RoI align -> A bf16 in W1-natural k order (c*49+bin)
  roi_kernel<<<1024, 192, 0, stream>>>(fmap, boxes, Aroi);
  // K2: GEMM1 [256 x 37632] @ W1 [37632 x 1024], 28 ks x 16 nt
  gemm_splitk<37632, 1024, 21, 16><<<448, 256, 0, stream>>>(Aroi, W1, part1);
  // K3: reduce + b1 + relu -> h bf16
  reduce_relu_28<<<256, 256, 0, stream>>>(part1, b1, h);
  // K4: GEMM2 [256 x 1024] @ W2 [1024 x 512], 8 ks x 8 nt
  gemm_splitk<1024, 512, 2, 8><<<64, 256, 0, stream>>>(h, W2, part2);
  // K5: reduce + b2 -> out
  reduce_bias_8<<<128, 256, 0, stream>>>(part2, b2, out);
}

// Round 4
// 340.805 us; speedup vs baseline: 1.1712x; 1.1712x over previous
//
#include <hip/hip_runtime.h>
#include <hip/hip_bf16.h>

typedef __attribute__((ext_vector_type(8))) short bfrag8;   // 8 bf16 (4 VGPRs)
typedef __attribute__((ext_vector_type(4))) float f32x4;    // MFMA C/D frag

__device__ __forceinline__ unsigned short f2bf(float f) {
  unsigned int u = __float_as_uint(f);
  u += 0x7FFFu + ((u >> 16) & 1u);   // RNE
  return (unsigned short)(u >> 16);
}

// torchvision _interp_axis semantics (aligned=false)
__device__ __forceinline__ void interp1(float t, int size, int& lo, int& hi, float& frac, bool& valid) {
  valid = (t > -1.0f) && (t < (float)size);
  t = fmaxf(t, 0.0f);
  lo = (int)t;                      // t>=0 so trunc == floor
  if (lo > size - 1) lo = size - 1;
  hi = lo + 1; if (hi > size - 1) hi = size - 1;
  if (lo >= size - 1) t = (float)lo;
  frac = t - (float)lo;
}

// ---------- K1: RoI align -> A[256][37632] bf16, k = c*49 + (ph*7+pw)  (W1-natural order) ----------
// grid 1024 = (box n, channel-quarter q). 384 threads: t = u*? no — cg = t%48 (float4 channel
// group, 4 ch), u = t/48 (bin-slot; thread owns bins {u, u+8, ...}). 48-lane runs share (y,x)
// -> 768 B contiguous per float4 load instr. Results go to LDS in final c-major layout,
// then coalesced uint2 copy-out.
__global__ __launch_bounds__(384) void roi_kernel(const float* __restrict__ fmap,
                                                  const float* __restrict__ boxes,
                                                  unsigned short* __restrict__ A) {
  const int bid = blockIdx.x;
  const int n = bid >> 2, q = bid & 3;
  const int t = threadIdx.x;
  const int cg = t % 48;          // channel group: channels c..c+3
  const int u  = t / 48;          // bin slot 0..7
  __shared__ unsigned short T[192 * 49];   // [cg*196 + j*49 + bin], 18816 B

  const float* bx = boxes + n * 5;
  const int b = (int)bx[0];
  const float x1 = bx[1], y1 = bx[2], x2 = bx[3], y2 = bx[4];
  const float bw = fmaxf(x2 - x1, 1.0f) * (1.0f / 7.0f);
  const float bh = fmaxf(y2 - y1, 1.0f) * (1.0f / 7.0f);

  const int c = q * 192 + cg * 4;
  const float* fb = fmap + (size_t)b * 64 * 64 * 768 + c;

  for (int bin = u; bin < 49; bin += 8) {
    const int ph = bin / 7;
    const int pw = bin - ph * 7;
    float a0 = 0.f, a1 = 0.f, a2 = 0.f, a3 = 0.f;
    #pragma unroll
    for (int sy = 0; sy < 2; sy++) {
      float yv = y1 + (ph * 2 + sy + 0.5f) * 0.5f * bh;
      int yl, yh; float fy; bool vy;
      interp1(yv, 64, yl, yh, fy, vy);
      const float gy = 1.0f - fy;
      #pragma unroll
      for (int sx = 0; sx < 2; sx++) {
        float xv = x1 + (pw * 2 + sx + 0.5f) * 0.5f * bw;
        int xl, xh; float fx; bool vx;
        interp1(xv, 64, xl, xh, fx, vx);
        if (vy && vx) {
          const float gx = 1.0f - fx;
          const float w00 = gy * gx, w01 = gy * fx, w10 = fy * gx, w11 = fy * fx;
          const float* r0 = fb + (size_t)(yl * 64) * 768;
          const float* r1 = fb + (size_t)(yh * 64) * 768;
          float4 v00 = *(const float4*)(r0 + (size_t)xl * 768);
          float4 v01 = *(const float4*)(r0 + (size_t)xh * 768);
          float4 v10 = *(const float4*)(r1 + (size_t)xl * 768);
          float4 v11 = *(const float4*)(r1 + (size_t)xh * 768);
          a0 += w00 * v00.x + w01 * v01.x + w10 * v10.x + w11 * v11.x;
          a1 += w00 * v00.y + w01 * v01.y + w10 * v10.y + w11 * v11.y;
          a2 += w00 * v00.z + w01 * v01.z + w10 * v10.z + w11 * v11.z;
          a3 += w00 * v00.w + w01 * v01.w + w10 * v10.w + w11 * v11.w;
        }
      }
    }
    const int base = cg * 196 + bin;
    T[base]       = f2bf(a0 * 0.25f);
    T[base + 49]  = f2bf(a1 * 0.25f);
    T[base + 98]  = f2bf(a2 * 0.25f);
    T[base + 147] = f2bf(a3 * 0.25f);
  }
  __syncthreads();
  // coalesced copy-out: block region = A[n][q*9408 .. +9408) shorts = 18816 B (8-aligned)
  const uint2* Ts = (const uint2*)T;
  uint2* outp = (uint2*)(A + (size_t)n * 37632 + q * 9408);
  for (int i = t; i < 2352; i += 384) outp[i] = Ts[i];
}

// ---------- K2/K4: split-K bf16 MFMA GEMM, BM=256 BN=64 BK=64 ----------
// A [256][KT] bf16 row-major (global_load_lds, source-swizzled, linear LDS dest).
// B [KT][NT] fp32 row-major, k-tile rows CONSECUTIVE -> coalesced 256-B segments.
// grid 1D = NKS*NNT, XCD-swizzled so all NNT n-tiles of a ks-chunk share an XCD (A L2 reuse).
template<int KT, int NT, int STEPS, int NNT>
__global__ __launch_bounds__(256, 2) void gemm_splitk(const unsigned short* __restrict__ A,
                                                      const float* __restrict__ B,
                                                      float* __restrict__ part) {
  __shared__ unsigned short Al[2][256 * 64];   // 64 KB, rows 128 B, swizzle key (r&7)
  __shared__ unsigned short Bl[2][64 * 64];    // 16 KB, [n][k] rows 128 B, key (n>>3)&7

  const int nwg = gridDim.x;
  const int bid = blockIdx.x;
  const int work = (bid & 7) * (nwg >> 3) + (bid >> 3);
  const int ks = work / NNT;
  const int nt = work - ks * NNT;
  const int n0 = nt * 64;
  const int k0 = ks * (STEPS * 64);

  const int t = (int)threadIdx.x;
  const int lane = t & 63, wid = t >> 6;

  f32x4 acc[4][4];
  #pragma unroll
  for (int i = 0; i < 4; i++)
    #pragma unroll
    for (int j = 0; j < 4; j++) acc[i][j] = (f32x4){0.f, 0.f, 0.f, 0.f};

  // B staging registers — NAMED, never address-taken (rule #20)
  float4 b00, b01, b10, b11;

  auto issueA = [&](int buf, int s) {
    #pragma unroll
    for (int i = 0; i < 8; i++) {
      const int r0 = wid * 64 + i * 8;               // 8 rows per 1KB instr
      const int row = r0 + (lane >> 3);
      const int j = (lane & 7) ^ (row & 7);          // pre-swizzled global slot
      const unsigned short* g = A + (size_t)row * KT + (k0 + s * 64 + j * 8);
      __builtin_amdgcn_global_load_lds(
          (const __attribute__((address_space(1))) void*)g,
          (__attribute__((address_space(3))) void*)&Al[buf][r0 * 64],
          16, 0, 0);
    }
  };

  // rows r = (t>>4)*2 + {0,1} + 32g  (consecutive rows; 16 lanes cover one row's 256 B)
  auto loadB = [&](int s) {
    const float* p = B + (size_t)(k0 + s * 64 + (t >> 4) * 2) * NT + n0 + (t & 15) * 4;
    b00 = *(const float4*)p;
    b01 = *(const float4*)(p + NT);
    b10 = *(const float4*)(p + 32 * (size_t)NT);
    b11 = *(const float4*)(p + 33 * (size_t)NT);
  };

  auto writeB = [&](int buf) {
    char* base = (char*)&Bl[buf][0];
    const int lo = ((t >> 4) & 3) * 4;      // byte-in-slot (k-pair position)
    const int nb = (t & 15) * 4;
    #define WRB(g, j, fa, fb_) { \
      int nn = nb + j; \
      int slot = (g) * 4 + wid; \
      unsigned v = (unsigned)f2bf(fa) | ((unsigned)f2bf(fb_) << 16); \
      *(unsigned*)(base + nn * 128 + ((slot ^ ((nn >> 3) & 7)) << 4) + lo) = v; }
    WRB(0, 0, b00.x, b01.x) WRB(0, 1, b00.y, b01.y)
    WRB(0, 2, b00.z, b01.z) WRB(0, 3, b00.w, b01.w)
    WRB(1, 0, b10.x, b11.x) WRB(1, 1, b10.y, b11.y)
    WRB(1, 2, b10.z, b11.z) WRB(1, 3, b10.w, b11.w)
    #undef WRB
  };

  auto compute = [&](int buf) {
    const char* abase = (const char*)&Al[buf][0];
    const char* bbase = (const char*)&Bl[buf][0];
    #pragma unroll
    for (int kk = 0; kk < 2; kk++) {
      const int slot = kk * 4 + (lane >> 4);
      bfrag8 af[4], bf[4];
      #pragma unroll
      for (int fm = 0; fm < 4; fm++) {
        const int r = wid * 64 + fm * 16 + (lane & 15);
        af[fm] = *(const bfrag8*)(abase + r * 128 + ((slot ^ (r & 7)) << 4));
      }
      #pragma unroll
      for (int fn = 0; fn < 4; fn++) {
        const int r = fn * 16 + (lane & 15);
        bf[fn] = *(const bfrag8*)(bbase + r * 128 + ((slot ^ ((r >> 3) & 7)) << 4));
      }
      #pragma unroll
      for (int fm = 0; fm < 4; fm++)
        #pragma unroll
        for (int fn = 0; fn < 4; fn++)
          acc[fm][fn] = __builtin_amdgcn_mfma_f32_16x16x32_bf16(af[fm], bf[fn], acc[fm][fn], 0, 0, 0);
    }
  };

  // prologue
  issueA(0, 0);
  loadB(0);
  writeB(0);
  __syncthreads();           // drains vmcnt(0): A-DMA + B loads complete

  int buf = 0;
  for (int s = 0; s < STEPS; s++) {
    if (s + 1 < STEPS) {
      issueA(buf ^ 1, s + 1);   // async DMA into other half
      loadB(s + 1);             // HBM latency hides under compute
    }
    compute(buf);
    if (s + 1 < STEPS) writeB(buf ^ 1);
    __syncthreads();
    buf ^= 1;
  }

  // epilogue: C/D layout col=lane&15, row=(lane>>4)*4+q
  const int r4 = (lane >> 4) * 4, cn = lane & 15;
  #pragma unroll
  for (int fm = 0; fm < 4; fm++)
    #pragma unroll
    for (int fn = 0; fn < 4; fn++)
      #pragma unroll
      for (int q = 0; q < 4; q++) {
        int m = wid * 64 + fm * 16 + r4 + q;
        part[((size_t)ks * 256 + m) * NT + n0 + fn * 16 + cn] = acc[fm][fn][q];
      }
}

// ---------- K3: reduce 28 partials + bias + relu -> h bf16 [256][1024] ----------
__global__ __launch_bounds__(256) void reduce_relu_28(const float* __restrict__ part,
                                                      const float* __restrict__ b1,
                                                      unsigned short* __restrict__ h) {
  const int i4 = blockIdx.x * 256 + threadIdx.x;   // over 65536 float4
  const float4* p4 = (const float4*)part;
  float4 s = p4[i4];
  #pragma unroll
  for (int p = 1; p < 28; p++) {
    float4 v = p4[(size_t)p * 65536 + i4];
    s.x += v.x; s.y += v.y; s.z += v.z; s.w += v.w;
  }
  float4 bb = ((const float4*)b1)[i4 & 255];
  s.x = fmaxf(s.x + bb.x, 0.f); s.y = fmaxf(s.y + bb.y, 0.f);
  s.z = fmaxf(s.z + bb.z, 0.f); s.w = fmaxf(s.w + bb.w, 0.f);
  uint2 pk;
  pk.x = (unsigned)f2bf(s.x) | ((unsigned)f2bf(s.y) << 16);
  pk.y = (unsigned)f2bf(s.z) | ((unsigned)f2bf(s.w) << 16);
  ((uint2*)h)[i4] = pk;
}

// ---------- K5: reduce 8 partials + bias -> out fp32 [256][512] ----------
__global__ __launch_bounds__(256) void reduce_bias_8(const float* __restrict__ part,
                                                     const float* __restrict__ b2,
                                                     float* __restrict__ out) {
  const int i4 = blockIdx.x * 256 + threadIdx.x;   // over 32768 float4
  const float4* p4 = (const float4*)part;
  float4 s = p4[i4];
  #pragma unroll
  for (int p = 1; p < 8; p++) {
    float4 v = p4[(size_t)p * 32768 + i4];
    s.x += v.x; s.y += v.y; s.z += v.z; s.w += v.w;
  }
  float4 bb = ((const float4*)b2)[i4 & 127];
  s.x += bb.x; s.y += bb.y; s.z += bb.z; s.w += bb.w;
  ((float4*)out)[i4] = s;
}

// ---------- launch ----------
extern "C" void kernel_launch(void* const* d_in, const int* in_sizes, int n_in,
                              void* d_out, int out_size, void* d_ws, size_t ws_size,
                              hipStream_t stream) {
  const float* fmap  = (const float*)d_in[0];
  const float* boxes = (const float*)d_in[1];
  const float* W1    = (const float*)d_in[2];
  const float* b1    = (const float*)d_in[3];
  const float* W2    = (const float*)d_in[4];
  const float* b2    = (const float*)d_in[5];
  float* out = (float*)d_out;

  char* ws = (char*)d_ws;
  unsigned short* Aroi = (unsigned short*)ws;                       // 19,267,584 B
  float* part1 = (float*)(ws + 19267584);                           // 29,360,128 B
  unsigned short* h = (unsigned short*)(ws + 19267584 + 29360128);  // 524,288 B
  float* part2 = (float*)(ws + 19267584 + 29360128 + 524288);       // 4,194,304 B

  // K1: RoI align -> A bf16 in W1-natural k order (c*49+bin)
  roi_kernel<<<1024, 384, 0, stream>>>(fmap, boxes, Aroi);
  // K2: GEMM1 [256 x 37632] @ W1 [37632 x 1024], 28 ks x 16 nt
  gemm_splitk<37632, 1024, 21, 16><<<448, 256, 0, stream>>>(Aroi, W1, part1);
  // K3: reduce + b1 + relu -> h bf16
  reduce_relu_28<<<256, 256, 0, stream>>>(part1, b1, h);
  // K4: GEMM2 [256 x 1024] @ W2 [1024 x 512], 8 ks x 8 nt
  gemm_splitk<1024, 512, 2, 8><<<64, 256, 0, stream>>>(h, W2, part2);
  // K5: reduce + b2 -> out
  reduce_bias_8<<<128, 256, 0, stream>>>(part2, b2, out);
}